// Round 8
// baseline (285.398 us; speedup 1.0000x reference)
//
#include <hip/hip_runtime.h>
#include <stdint.h>

typedef __bf16 bf16_t;
typedef bf16_t bf16x4 __attribute__((ext_vector_type(4)));
typedef bf16_t bf16x8 __attribute__((ext_vector_type(8)));
typedef float f32x4 __attribute__((ext_vector_type(4)));

#define DIM 256
#define NNODES 50000

// ---------------- edge dtype detection (int64 vs int32) ----------------
__global__ void detect_kernel(const int* __restrict__ ei, int* __restrict__ flags) {
    __shared__ int s_zero;
    if (threadIdx.x == 0) s_zero = 0;
    __syncthreads();
    int z = (ei[2 * threadIdx.x + 1] == 0) ? 1 : 0;   // odd words: int64 high halves == 0
    atomicAdd(&s_zero, z);
    __syncthreads();
    if (threadIdx.x == 0) flags[0] = (s_zero > 128) ? 1 : 0;
}

__device__ __forceinline__ int load_edge(const int* __restrict__ ei, int E, int f64,
                                         int which /*0=src,1=dst*/, int e) {
    int v = f64 ? ei[(size_t)which * 2 * E + 2 * (size_t)e]   // int64 low word (LE)
                : ei[(size_t)which * E + (size_t)e];
    return min(max(v, 0), NNODES - 1);
}

// ---------------- CSR build ----------------

__global__ void zero_counts_kernel(int* __restrict__ counts, int n) {
    int i = blockIdx.x * blockDim.x + threadIdx.x;
    if (i < n) counts[i] = 0;
}

__global__ void hist_kernel(const int* __restrict__ ei, int E, const int* __restrict__ flags,
                            int* __restrict__ counts) {
    int e = blockIdx.x * blockDim.x + threadIdx.x;
    if (e < E) atomicAdd(&counts[load_edge(ei, E, flags[0], 1, e)], 1);
}

__global__ __launch_bounds__(256) void scanA_kernel(const int* __restrict__ counts,
                                                    int* __restrict__ offsets,
                                                    int* __restrict__ bsums, int n) {
    __shared__ int sm[256];
    int b = blockIdx.x, t = threadIdx.x;
    int idx = b * 256 + t;
    int v = (idx < n) ? counts[idx] : 0;
    sm[t] = v;
    __syncthreads();
    #pragma unroll
    for (int off = 1; off < 256; off <<= 1) {
        int u = (t >= off) ? sm[t - off] : 0;
        __syncthreads();
        sm[t] += u;
        __syncthreads();
    }
    if (idx < n) offsets[idx + 1] = sm[t];
    if (t == 255) bsums[b] = sm[255];
}

__global__ __launch_bounds__(256) void scanB_kernel(int* __restrict__ bsums, int nb) {
    __shared__ int sm[256];
    int t = threadIdx.x;
    int v = (t < nb) ? bsums[t] : 0;
    sm[t] = v;
    __syncthreads();
    #pragma unroll
    for (int off = 1; off < 256; off <<= 1) {
        int u = (t >= off) ? sm[t - off] : 0;
        __syncthreads();
        sm[t] += u;
        __syncthreads();
    }
    if (t < nb) bsums[t] = sm[t] - v;
}

__global__ __launch_bounds__(256) void scanC_kernel(const int* __restrict__ counts,
                                                    const int* __restrict__ bsums,
                                                    int* __restrict__ offsets,
                                                    float* __restrict__ dinv,
                                                    int* __restrict__ cursor, int n) {
    int b = blockIdx.x;
    int idx = b * 256 + threadIdx.x;
    if (idx == 0) offsets[0] = 0;
    if (idx < n) {
        int incl = offsets[idx + 1] + bsums[b];
        offsets[idx + 1] = incl;
        cursor[idx] = incl - counts[idx];
        dinv[idx] = rsqrtf((float)(counts[idx] + 1));  // +1 self-loop
    }
}

__global__ void scatter_kernel(const int* __restrict__ ei, int E, const int* __restrict__ flags,
                               const float* __restrict__ dinv, int* __restrict__ cursor,
                               int* __restrict__ csr_src, float* __restrict__ csr_norm) {
    int e = blockIdx.x * blockDim.x + threadIdx.x;
    if (e < E) {
        int s = load_edge(ei, E, flags[0], 0, e);
        int d = load_edge(ei, E, flags[0], 1, e);
        int pos = atomicAdd(&cursor[d], 1);
        if (pos >= 0 && pos < E) {
            csr_src[pos] = s;
            csr_norm[pos] = dinv[s] * dinv[d];
        }
    }
}

// ---------------- weight prep: fp32 W[k][n] -> fragment-order bf16 Wf ----------------
// Wf layout: slice s = k>>5; B-frag for (nt, lane) at short index s*8192 + nt*512 + lane*8,
// element j corresponds to W[k = s*32 + (lane>>4)*8 + j][n = nt*16 + (lane&15)].
// Wave B-frag load = contiguous 1 KB from L2 — no LDS needed.

__global__ void convert_w_kernel(const float* __restrict__ W1, const float* __restrict__ W2,
                                 bf16_t* __restrict__ Wf1, bf16_t* __restrict__ Wf2) {
    const float* W = blockIdx.y ? W2 : W1;
    bf16_t* Wf = blockIdx.y ? Wf2 : Wf1;
    int k = blockIdx.x, n = threadIdx.x;      // read W[k][n] coalesced per block
    int s = k >> 5, quad = (k >> 3) & 3, j = k & 7;
    int nt = n >> 4, m = n & 15;
    Wf[s * 8192 + (nt * 64 + quad * 16 + m) * 8 + j] = (bf16_t)W[k * DIM + n];
}

// ---------------- GEMM: H[M,256](bf16) = X[M,256] @ W ----------------
// 1 row-tile (16 rows) per wave, 4 waves/block, grid = 782 (~3 blocks/CU).
// B-fragments read directly from L2-resident Wf (128 KB) — no LDS, no barriers.

template <bool F32A>
__global__ __launch_bounds__(256, 4) void gemm_kernel(const void* __restrict__ Xv,
                                                      const bf16_t* __restrict__ Wf,
                                                      bf16_t* __restrict__ H, int tiles) {
    int tid = threadIdx.x;
    int wave = tid >> 6, lane = tid & 63;
    int m = lane & 15, quad = lane >> 4;
    int tile = blockIdx.x * 4 + wave;
    bool active = tile < tiles;
    int arow = (min(tile, tiles - 1)) * 16 + m;   // clamped; store predicated below

    f32x4 acc[16] = {};
    const bf16_t* wbase = Wf + lane * 8;

    #pragma unroll 2
    for (int s = 0; s < 8; s++) {
        // A fragment: A[m=lane&15][k = s*32 + quad*8 + j]
        bf16x8 a;
        if (F32A) {
            const f32x4* xp = (const f32x4*)((const float*)Xv + (size_t)arow * DIM + s * 32 + quad * 8);
            f32x4 x0 = xp[0], x1 = xp[1];
            #pragma unroll
            for (int j = 0; j < 4; j++) { a[j] = (bf16_t)x0[j]; a[j + 4] = (bf16_t)x1[j]; }
        } else {
            a = *(const bf16x8*)((const bf16_t*)Xv + (size_t)arow * DIM + s * 32 + quad * 8);
        }

        const bf16_t* ws = wbase + s * 8192;
        #pragma unroll
        for (int nt = 0; nt < 16; nt++) {
            bf16x8 b = *(const bf16x8*)(ws + nt * 512);   // wave: contiguous 1 KB, L2-hit
            acc[nt] = __builtin_amdgcn_mfma_f32_16x16x32_bf16(a, b, acc[nt], 0, 0, 0);
        }
    }

    if (active) {
        int rowb = tile * 16 + quad * 4;
        #pragma unroll
        for (int nt = 0; nt < 16; nt++) {
            #pragma unroll
            for (int r = 0; r < 4; r++) {
                H[(size_t)(rowb + r) * DIM + nt * 16 + m] = (bf16_t)acc[nt][r];
            }
        }
    }
}

// ---------------- Aggregation: bf16 H gather, fp32 accumulate ----------------

template <bool OUT_BF16>
__global__ __launch_bounds__(256) void aggregate_kernel(const bf16_t* __restrict__ H,
                                                        const int* __restrict__ offsets,
                                                        const int* __restrict__ csr_src,
                                                        const float* __restrict__ csr_norm,
                                                        const float* __restrict__ dinv,
                                                        const float* __restrict__ bias,
                                                        void* __restrict__ outv, int n) {
    int g = threadIdx.x >> 6;
    int l = threadIdx.x & 63;
    int i = blockIdx.x * 4 + g;
    if (i >= n) return;
    float dii = dinv[i];

    auto cvt = [](bf16x4 v) -> f32x4 {
        f32x4 r;
        #pragma unroll
        for (int j = 0; j < 4; j++) r[j] = (float)v[j];
        return r;
    };

    f32x4 acc = cvt(*(const bf16x4*)(H + (size_t)i * DIM + l * 4)) * (dii * dii);
    int e0 = offsets[i], e1 = offsets[i + 1];
    int e = e0;
    for (; e + 4 <= e1; e += 4) {
        int s0 = csr_src[e], s1 = csr_src[e + 1], s2 = csr_src[e + 2], s3 = csr_src[e + 3];
        float w0 = csr_norm[e], w1 = csr_norm[e + 1], w2 = csr_norm[e + 2], w3 = csr_norm[e + 3];
        bf16x4 h0 = *(const bf16x4*)(H + (size_t)s0 * DIM + l * 4);
        bf16x4 h1 = *(const bf16x4*)(H + (size_t)s1 * DIM + l * 4);
        bf16x4 h2 = *(const bf16x4*)(H + (size_t)s2 * DIM + l * 4);
        bf16x4 h3 = *(const bf16x4*)(H + (size_t)s3 * DIM + l * 4);
        acc += cvt(h0) * w0 + cvt(h1) * w1 + cvt(h2) * w2 + cvt(h3) * w3;
    }
    for (; e < e1; e++) {
        acc += cvt(*(const bf16x4*)(H + (size_t)csr_src[e] * DIM + l * 4)) * csr_norm[e];
    }
    acc += *(const f32x4*)(bias + l * 4);
    #pragma unroll
    for (int j = 0; j < 4; j++) acc[j] = fmaxf(acc[j], 0.0f);

    if (OUT_BF16) {
        bf16x4 o;
        #pragma unroll
        for (int j = 0; j < 4; j++) o[j] = (bf16_t)acc[j];
        *(bf16x4*)((bf16_t*)outv + (size_t)i * DIM + l * 4) = o;
    } else {
        *(f32x4*)((float*)outv + (size_t)i * DIM + l * 4) = acc;
    }
}

// ---------------- launch ----------------

extern "C" void kernel_launch(void* const* d_in, const int* in_sizes, int n_in,
                              void* d_out, int out_size, void* d_ws, size_t ws_size,
                              hipStream_t stream) {
    const float* x  = (const float*)d_in[0];
    const int*   ei = (const int*)d_in[1];
    const float* W1 = (const float*)d_in[2];
    const float* b1 = (const float*)d_in[3];
    const float* W2 = (const float*)d_in[4];
    const float* b2 = (const float*)d_in[5];
    float* out = (float*)d_out;

    const int n = NNODES;
    const int E = in_sizes[1] / 2;
    const int nb = (n + 255) / 256;

    char* ws = (char*)d_ws;
    size_t off = 0;
    auto alloc = [&](size_t bytes) -> char* {
        char* p = ws + off;
        off += (bytes + 255) & ~(size_t)255;
        return p;
    };
    int*    flags    = (int*)alloc(256);
    float*  dinv     = (float*)alloc((size_t)n * 4);
    int*    counts   = (int*)alloc((size_t)n * 4);
    int*    offsets  = (int*)alloc((size_t)(n + 1) * 4);
    int*    cursor   = (int*)alloc((size_t)n * 4);
    int*    bsums    = (int*)alloc((size_t)nb * 4);
    int*    csr_src  = (int*)alloc((size_t)E * 4);
    float*  csr_norm = (float*)alloc((size_t)E * 4);
    bf16_t* Wf1      = (bf16_t*)alloc((size_t)DIM * DIM * 2);
    bf16_t* Wf2      = (bf16_t*)alloc((size_t)DIM * DIM * 2);
    bf16_t* P        = (bf16_t*)alloc((size_t)n * DIM * 2);   // GEMM output (bf16)
    bf16_t* X2       = (bf16_t*)alloc((size_t)n * DIM * 2);   // inter-layer activation (bf16)

    detect_kernel<<<1, 256, 0, stream>>>(ei, flags);
    zero_counts_kernel<<<nb, 256, 0, stream>>>(counts, n);
    hist_kernel<<<(E + 255) / 256, 256, 0, stream>>>(ei, E, flags, counts);
    scanA_kernel<<<nb, 256, 0, stream>>>(counts, offsets, bsums, n);
    scanB_kernel<<<1, 256, 0, stream>>>(bsums, nb);
    scanC_kernel<<<nb, 256, 0, stream>>>(counts, bsums, offsets, dinv, cursor, n);
    scatter_kernel<<<(E + 255) / 256, 256, 0, stream>>>(ei, E, flags, dinv, cursor,
                                                        csr_src, csr_norm);

    convert_w_kernel<<<dim3(DIM, 2), DIM, 0, stream>>>(W1, W2, Wf1, Wf2);

    int tiles = (n + 15) / 16;                 // 3125 (exact: 50000 = 16*3125)
    int gemm_blocks = (tiles + 3) / 4;         // 782
    int agg_blocks = n / 4;                    // 12500

    gemm_kernel<true><<<gemm_blocks, 256, 0, stream>>>(x, Wf1, P, tiles);
    aggregate_kernel<true><<<agg_blocks, 256, 0, stream>>>(P, offsets, csr_src, csr_norm,
                                                           dinv, b1, X2, n);
    gemm_kernel<false><<<gemm_blocks, 256, 0, stream>>>(X2, Wf2, P, tiles);
    aggregate_kernel<false><<<agg_blocks, 256, 0, stream>>>(P, offsets, csr_src, csr_norm,
                                                            dinv, b2, out, n);
}